// Round 5
// baseline (692.514 us; speedup 1.0000x reference)
//
#include <hip/hip_runtime.h>
#include <hip/hip_bf16.h>

// Cutie memory read: sim = (-mk^2·qe + 2·mk·qk·qe - qe·qk^2)·ms/sqrt(64),
// affinity = softmax_n(sim), out = value @ affinity.
// qe>=0 -> sim <= 0 -> exp(sim) <= 1: no max pass; store es=exp(sim),
// normalize by per-p sum at the end.
// R6: gemm_big 256x256 (512 thr, 8 waves, split-K 6).
// R7: XCD-chunked bijective block swizzle: FETCH 788->134 MB (proven).
// R8/R9: counted-vmcnt schedule, exact tail drain (proven, +18%).
// R10: 3-region A (160 KB LDS) + fused normalize. Deeper vmcnt cover was
//      NEUTRAL -> latency cover not the limiter; barriers/LDS-pipe are.
// R11: 2 phases / 2 barriers per tile (was 4/8). 3-region A makes the
//      extra barriers unnecessary: A(t+2) stages into a region nobody
//      reads this tile; B(t+2) stages after ph0's barrier (B(t) reads
//      done). vmcnt ledger identical to R9 (8 in flight, tail drain-0).

#define NTOT 25920   // memory elements (16*30*54)
#define PTOT 1620    // query pixels (30*54)
#define VTOT 1536    // O*CV = 3*512
#define PPAD 1664    // 13*128 (sim grid padding)
#define PPAD2 1792   // 7*256  (gemm p padding; es has this many rows)
#define NPAD 25984   // 203*128
#define KF   128     // packed feature dim (2*CK)
#define SPLITS 6

typedef __hip_bfloat16 bf16;
using frag  = __attribute__((ext_vector_type(8))) short;   // 8 bf16 = 4 VGPR
using f32x4 = __attribute__((ext_vector_type(4))) float;

#define GLOBAL_AS __attribute__((address_space(1)))
#define LDS_AS    __attribute__((address_space(3)))
__device__ __forceinline__ void async_copy16(void* l, const void* g) {
    // per-lane 16B global chunk -> LDS at (wave-uniform base) + lane*16
    __builtin_amdgcn_global_load_lds((const GLOBAL_AS void*)g, (LDS_AS void*)l,
                                     16, 0, 0);
}

// ---------------- ws layout (bytes) ----------------
#define OFF_FLAG ((size_t)0)                    // u32 dtype flag (64 B reserved)
#define OFF_QF   ((size_t)64)                   // bf16 [PPAD][KF]
#define OFF_NF   ((size_t)426048)               // bf16 [NPAD][KF]
#define OFF_BSQ  ((size_t)7077952)              // f32  [PPAD]
#define OFF_MSC  ((size_t)7084608)              // f32  [NPAD]
#define OFF_SUM  ((size_t)7188544)              // f32  [PPAD]
#define OFF_ACC  ((size_t)7195200)              // f32  [VTOT][PTOT] (unused)
#define OFF_ES   ((size_t)17148480)             // bf16 [PPAD2][NTOT] 92,897,280 B
#define OFF_VALB ((size_t)110045760)            // bf16 [VTOT][NTOT]  79,626,240 B
#define NEED_BIG ((size_t)189672000)

// ---- dtype detector (bf16 N(0,1) never has exponent >= 0x8F)
__global__ void detect_dtype(const unsigned short* __restrict__ mk16,
                             unsigned* __restrict__ flag) {
    int i = threadIdx.x;            // 32 threads, parallel loads
    unsigned e = (mk16[2 * i] >> 7) & 0xFFu;
    unsigned long long bad = __ballot(e >= 0x8Fu);
    if (i == 0) *flag = bad ? 1u : 0u;   // 1 = fp32 inputs, 0 = bf16 inputs
}

__device__ __forceinline__ float load_in(const void* p, int idx, bool f32) {
    return f32 ? ((const float*)p)[idx]
               : __bfloat162float(((const bf16*)p)[idx]);
}

// ---- pass 0a: qf[p][c]=-qe, qf[p][64+c]=2*qk*qe; bsq; zero sums
__global__ __launch_bounds__(256) void prep_q(const void* __restrict__ key,
                                              const void* __restrict__ sel,
                                              bf16* __restrict__ qf,
                                              float* __restrict__ bsq,
                                              float* __restrict__ sums,
                                              const unsigned* __restrict__ flag) {
    const bool f32 = (*flag != 0u);
    int p = blockIdx.x * 256 + threadIdx.x;
    if (p >= PPAD) return;
    float acc = 0.f;
    for (int c = 0; c < 64; ++c) {
        float qk = 0.f, qe = 0.f;
        if (p < PTOT) {
            qk = load_in(key, c * PTOT + p, f32);
            qe = load_in(sel, c * PTOT + p, f32);
        }
        qf[p * KF + c]      = __float2bfloat16(-qe);
        qf[p * KF + 64 + c] = __float2bfloat16(2.f * qk * qe);
        acc += qe * qk * qk;
    }
    bsq[p]  = acc;
    sums[p] = 0.f;
}

// ---- pass 0b: nf[n][c]=mk^2, nf[n][64+c]=mk; msc=ms/8
__global__ __launch_bounds__(256) void prep_n(const void* __restrict__ mkey,
                                              const void* __restrict__ shr,
                                              bf16* __restrict__ nf,
                                              float* __restrict__ msc,
                                              const unsigned* __restrict__ flag) {
    const bool f32 = (*flag != 0u);
    int n = blockIdx.x * 256 + threadIdx.x;
    if (n >= NPAD) return;
    for (int c = 0; c < 64; ++c) {
        float mk = (n < NTOT) ? load_in(mkey, c * NTOT + n, f32) : 0.f;
        nf[n * KF + c]      = __float2bfloat16(mk * mk);
        nf[n * KF + 64 + c] = __float2bfloat16(mk);
    }
    msc[n] = (n < NTOT) ? load_in(shr, n, f32) * 0.125f : 0.f;
}

// ---- pass 0c (big path): val -> bf16, 8 elements per thread
__global__ __launch_bounds__(256) void conv_val(const void* __restrict__ val,
                                                bf16* __restrict__ valb,
                                                const unsigned* __restrict__ flag) {
    const bool f32 = (*flag != 0u);
    size_t base = ((size_t)blockIdx.x * 256 + threadIdx.x) * 8;
    if (base >= (size_t)VTOT * NTOT) return;
    if (f32) {
        const float4 v0 = *(const float4*)((const float*)val + base);
        const float4 v1 = *(const float4*)((const float*)val + base + 4);
        bf16 o[8] = {__float2bfloat16(v0.x), __float2bfloat16(v0.y),
                     __float2bfloat16(v0.z), __float2bfloat16(v0.w),
                     __float2bfloat16(v1.x), __float2bfloat16(v1.y),
                     __float2bfloat16(v1.z), __float2bfloat16(v1.w)};
        *(uint4*)(valb + base) = *(const uint4*)o;
    } else {
        *(uint4*)(valb + base) = *(const uint4*)((const bf16*)val + base);
    }
}

// ---- pass 1: sim GEMM (p-tile 128 x n-tile 128, K=128) + exp + row sums
// Swizzled LDS: 16B chunk c of row r stored at chunk position c ^ (r&15).
#define EST_LD 136   // shorts; 272 B row stride, 16B-aligned
__global__ __launch_bounds__(256) void sim_kernel(const bf16* __restrict__ qf,
                                                  const bf16* __restrict__ nf,
                                                  const float* __restrict__ bsq,
                                                  const float* __restrict__ msc,
                                                  float* __restrict__ sums,
                                                  bf16* __restrict__ es) {
    __shared__ __align__(16) char smem[65536];
    short* As  = (short*)smem;            // [128][KF] swizzled
    short* Bs  = (short*)(smem + 32768);  // [128][KF] swizzled
    short* Est = (short*)smem;            // [128][EST_LD] (aliases As/Bs)

    const int tid = threadIdx.x;
    const int nt = blockIdx.x, pt = blockIdx.y;
    const int p0 = pt * 128, n0 = nt * 128;
    const int w = tid >> 6, lane = tid & 63;

    // async stage with source-side swizzle: rows are 256 B = 16 chunks
    for (int it = 0; it < 8; ++it) {
        int rb = it * 16 + w * 4;
        int r  = rb + (lane >> 4);
        int cg = (lane & 15) ^ (r & 15);
        async_copy16(&As[rb * KF], qf + (size_t)(p0 + r) * KF + cg * 8);
    }
    for (int it = 0; it < 8; ++it) {
        int rb = it * 16 + w * 4;
        int r  = rb + (lane >> 4);
        int cg = (lane & 15) ^ (r & 15);
        async_copy16(&Bs[rb * KF], nf + (size_t)(n0 + r) * KF + cg * 8);
    }
    __syncthreads();

    const int low = lane & 15, quad = lane >> 4;
    const int wr = w >> 1, wc = w & 1;

    f32x4 acc[4][4] = {};
    for (int kk = 0; kk < 4; ++kk) {
        frag a[4], b[4];
        for (int i = 0; i < 4; ++i) {
            int row = wr * 64 + i * 16 + low;          // row & 15 == low
            a[i] = *(const frag*)&As[row * KF + (((kk * 4 + quad) ^ low) * 8)];
        }
        for (int j = 0; j < 4; ++j) {
            int row = wc * 64 + j * 16 + low;
            b[j] = *(const frag*)&Bs[row * KF + (((kk * 4 + quad) ^ low) * 8)];
        }
        for (int i = 0; i < 4; ++i)
            for (int j = 0; j < 4; ++j)
                acc[i][j] = __builtin_amdgcn_mfma_f32_16x16x32_bf16(a[i], b[j], acc[i][j], 0, 0, 0);
    }

    float msv[4];
    for (int j = 0; j < 4; ++j) msv[j] = msc[n0 + wc * 64 + j * 16 + low];
    __syncthreads();   // all fragment reads done before Est overwrites As/Bs

    for (int i = 0; i < 4; ++i) {
        const int prow = p0 + wr * 64 + i * 16 + quad * 4;
        const float4 bq = *(const float4*)(bsq + prow);
        const float bs[4] = {bq.x, bq.y, bq.z, bq.w};
        for (int r = 0; r < 4; ++r) {
            const int p = prow + r;
            const int rloc = wr * 64 + i * 16 + quad * 4 + r;
            float vsum = 0.f;
            for (int j = 0; j < 4; ++j) {
                const int n = n0 + wc * 64 + j * 16 + low;
                float e = 0.f;
                if (n < NTOT) e = __expf((acc[i][j][r] - bs[r]) * msv[j]);
                vsum += e;
                Est[rloc * EST_LD + wc * 64 + j * 16 + low] = __bfloat16_as_short(__float2bfloat16(e));
            }
            vsum += __shfl_xor(vsum, 1);
            vsum += __shfl_xor(vsum, 2);
            vsum += __shfl_xor(vsum, 4);
            vsum += __shfl_xor(vsum, 8);
            if (p < PTOT && low == 0) atomicAdd(&sums[p], vsum);
        }
    }
    __syncthreads();

    // vectorized store: thread -> (row, half); 8 x uint4 per thread
    const int row = tid >> 1, half = tid & 1;
    const int p = p0 + row;
    if (p < PTOT) {
        bf16* dst = es + (size_t)p * NTOT + n0 + half * 64;
        const short* src = Est + row * EST_LD + half * 64;
        for (int m = 0; m < 8; ++m) {
            int ng = n0 + half * 64 + m * 8;
            if (ng + 8 <= NTOT)
                *(uint4*)(dst + m * 8) = *(const uint4*)(src + m * 8);
        }
    }
}

// ---- pass 2a (big): 256x256 readout GEMM, 2-phase/2-barrier tiles (R11).
// Waves: wv = v-half (128 rows), wp = p-quarter (64 rows). acc[8][4].
// LDS: As[3][2][128*64] (A regions rotate t%3, 96 KB) +
//      Bs[2][2][128*64] (B regions t&1, 64 KB) = 160 KB.
// Per tile t:
//   ph0: stage A(t+2) (region nx2, free); read B(t) frags (regs, whole
//        tile) + A i=0..3; lgkmcnt(0); setprio; 32 MFMA; barrier.
//   ph1: stage B(t+2) (region t&1; B(t) reads done at ph0 barrier);
//        read A i=4..7; lgkmcnt(0); setprio; 32 MFMA; vmcnt(8|0); barrier.
// vmcnt ledger: steady t-end leaves A(t+2),B(t+2) (newest 8) in flight,
// drains A(t+1),B(t+1) before t+1 reads them. Tail: t+2>=ke -> vmcnt(0).
// Epilogue: fused normalize (x 1/sums[p]) + atomicAdd into out.
__global__ __launch_bounds__(512) void gemm_big(const bf16* __restrict__ val,
                                                const bf16* __restrict__ es,
                                                const float* __restrict__ sums,
                                                float* __restrict__ out) {
    __shared__ __align__(16) short As[3][2][128 * 64];   // v rows (96 KB)
    __shared__ __align__(16) short Bs[2][2][128 * 64];   // p rows (64 KB)
    const int tid = threadIdx.x;

    // bijective XCD chunking (m204): consecutive orig ids round-robin XCDs.
    const int nwg = (PPAD2 / 256) * (VTOT / 256) * SPLITS;   // 252
    const int orig = blockIdx.x;
    const int xcd = orig & 7;
    const int q8 = nwg >> 3, r8 = nwg & 7;                   // 31, 4
    const int cbase = (xcd < r8) ? xcd * (q8 + 1) : r8 * (q8 + 1) + (xcd - r8) * q8;
    const int wg = cbase + (orig >> 3);
    const int vt = wg % 6;
    const int t2 = wg / 6;
    const int pt = t2 % 7;
    const int s  = t2 / 7;

    const int p0 = pt * 256, v0 = vt * 256;
    const int ks = s * 68;
    const int ke = (ks + 68 < 405) ? ks + 68 : 405;

    const int w = tid >> 6, lane = tid & 63, low = lane & 15, quad = lane >> 4;
    const int wv = w >> 2, wp = w & 3;     // wv: v half (128), wp: p quarter (64)
    const int rA = lane >> 3;              // 0..7 within 8-row group
    const int cgx = (lane & 7) ^ rA;       // swizzled source chunk (rb%8==0)

    // stage one half-tile (128 rows x 64 k) = 2 global_load_lds per wave
    auto stageA = [&](int t, int reg, int h) {
        if (t >= ke) return;
        const int k0 = t * 64;
#pragma unroll
        for (int it = 0; it < 2; ++it) {
            int rb = it * 64 + w * 8;
            async_copy16(&As[reg][h][rb * 64],
                         val + (size_t)(v0 + h * 128 + rb + rA) * NTOT + k0 + cgx * 8);
        }
    };
    auto stageB = [&](int t, int h) {
        if (t >= ke) return;
        const int k0 = t * 64, bb = t & 1;
#pragma unroll
        for (int it = 0; it < 2; ++it) {
            int rb = it * 64 + w * 8;
            async_copy16(&Bs[bb][h][rb * 64],
                         es + (size_t)(p0 + h * 128 + rb + rA) * NTOT + k0 + cgx * 8);
        }
    };

    const int hB = wp >> 1;                 // this wave's B half
    const int rB0 = (wp & 1) * 64 + low;    // B row-in-half base (+ j*16)
    const int c0 = ((0 * 4 + quad) ^ (low & 7)) * 8;   // kk=0 column (shorts)
    const int c1 = ((1 * 4 + quad) ^ (low & 7)) * 8;   // kk=1 column

    f32x4 acc[8][4] = {};

    // prologue: A(ks), B(ks), A(ks+1), B(ks+1); vmcnt(8) -> A(ks),B(ks)
    // landed, A(ks+1),B(ks+1) in flight.
    int cur = ks % 3;                        // A region of tile ks
    int nx1 = (cur + 1 == 3) ? 0 : cur + 1;  // region of ks+1
    stageA(ks, cur, 0); stageA(ks, cur, 1);
    stageB(ks, 0);      stageB(ks, 1);
    stageA(ks + 1, nx1, 0); stageA(ks + 1, nx1, 1);
    stageB(ks + 1, 0);      stageB(ks + 1, 1);
    asm volatile("s_waitcnt vmcnt(8)" ::: "memory");
    __builtin_amdgcn_s_barrier();

    for (int t = ks; t < ke; ++t) {
        int nx2 = cur + 2; if (nx2 >= 3) nx2 -= 3;   // region of t+2
        const short* Ab = As[cur][wv];
        const short* Bb = Bs[t & 1][hB];

        // ---------------- phase 0 ----------------
        stageA(t + 2, nx2, 0); stageA(t + 2, nx2, 1);

        frag bfr[2][4];                      // B held in regs across the tile
#pragma unroll
        for (int j = 0; j < 4; ++j) {
            bfr[0][j] = *(const frag*)&Bb[(rB0 + j * 16) * 64 + c0];
            bfr[1][j] = *(const frag*)&Bb[(rB0 + j * 16) * 64 + c1];
        }
        frag a0[4][2];                       // A i=0..3
#pragma unroll
        for (int ii = 0; ii < 4; ++ii) {
            const short* r = &Ab[(ii * 16 + low) * 64];
            a0[ii][0] = *(const frag*)&r[c0];
            a0[ii][1] = *(const frag*)&r[c1];
        }
        asm volatile("s_waitcnt lgkmcnt(0)" ::: "memory");
        __builtin_amdgcn_s_setprio(1);
#pragma unroll
        for (int ii = 0; ii < 4; ++ii)
#pragma unroll
            for (int j = 0; j < 4; ++j) {
                acc[ii][j] = __builtin_amdgcn_mfma_f32_16x16x32_bf16(a0[ii][0], bfr[0][j], acc[ii][j], 0, 0, 0);
                acc[ii][j] = __builtin_amdgcn_mfma_f32_16x16x32_bf16(a0[ii][1], bfr[1][j], acc[ii][j], 0, 0, 0);
            }
        __builtin_amdgcn_s_setprio(0);
        __builtin_amdgcn_s_barrier();        // B(t) reads complete block-wide

        // ---------------- phase 1 ----------------
        stageB(t + 2, 0); stageB(t + 2, 1);

        frag a1[4][2];                       // A i=4..7
#pragma unroll
        for (int ii = 0; ii < 4; ++ii) {
            const short* r = &Ab[((ii + 4) * 16 + low) * 64];
            a1[ii][0] = *(const frag*)&r[c0];
            a1[ii][1] = *(const frag*)&r[c1];
        }
        asm volatile("s_waitcnt lgkmcnt(0)" ::: "memory");
        __builtin_amdgcn_s_setprio(1);
#pragma unroll
        for (int ii = 0; ii < 4; ++ii)
#pragma unroll
            for (int j = 0; j < 4; ++j) {
                acc[ii + 4][j] = __builtin_amdgcn_mfma_f32_16x16x32_bf16(a1[ii][0], bfr[0][j], acc[ii + 4][j], 0, 0, 0);
                acc[ii + 4][j] = __builtin_amdgcn_mfma_f32_16x16x32_bf16(a1[ii][1], bfr[1][j], acc[ii + 4][j], 0, 0, 0);
            }
        __builtin_amdgcn_s_setprio(0);
        // Exact drain ledger (proven R9): steady leaves A(t+2),B(t+2)
        // (newest 8) in flight; tail (t+2 skipped) drains fully.
        if (t + 2 < ke)
            asm volatile("s_waitcnt vmcnt(8)" ::: "memory");
        else
            asm volatile("s_waitcnt vmcnt(0)" ::: "memory");
        __builtin_amdgcn_s_barrier();

        cur = nx1; nx1 = nx2;
    }

    // fused normalize + atomic accumulate into out
    float rs[4];
#pragma unroll
    for (int j = 0; j < 4; ++j) {
        const int p = p0 + wp * 64 + j * 16 + low;
        rs[j] = (p < PTOT) ? 1.0f / sums[p] : 0.f;
    }
#pragma unroll
    for (int i = 0; i < 8; ++i)
#pragma unroll
        for (int r = 0; r < 4; ++r) {
            const int v = v0 + wv * 128 + i * 16 + quad * 4 + r;
#pragma unroll
            for (int j = 0; j < 4; ++j) {
                const int p = p0 + wp * 64 + j * 16 + low;
                if (p < PTOT)
                    atomicAdd(&out[(size_t)v * PTOT + p], acc[i][j][r] * rs[j]);
            }
        }
}

// ---- pass 2b (small ws): fallback readout GEMM (128-tiles, unswizzled)
__global__ __launch_bounds__(256) void gemm_small(const void* __restrict__ val,
                                                  const bf16* __restrict__ es,
                                                  const float* __restrict__ sums,
                                                  float* __restrict__ out,
                                                  const unsigned* __restrict__ flag) {
    __shared__ short As[128 * 64];
    __shared__ short Bs[128 * 64];
    const bool f32 = (*flag != 0u);
    const int tid = threadIdx.x;
    const int pt = blockIdx.x, vt = blockIdx.y, s = blockIdx.z;
    const int p0 = pt * 128, v0 = vt * 128;
    const int ks = s * 51;
    const int ke = (ks + 51 < 405) ? ks + 51 : 405;

    const int w = tid >> 6, lane = tid & 63, low = lane & 15, quad = lane >> 4;
    const int wr = w >> 1, wc = w & 1;

    f32x4 acc[4][4] = {};
    for (int kt = ks; kt < ke; ++kt) {
        const int k0 = kt * 64;
        if (f32) {
            for (int it = 0; it < 8; ++it) {
                int ci = it * 256 + tid, row = ci >> 4, c4 = ci & 15;
                const float4 v = *(const float4*)((const float*)val +
                                  (size_t)(v0 + row) * NTOT + k0 + c4 * 4);
                bf16 o[4] = {__float2bfloat16(v.x), __float2bfloat16(v.y),
                             __float2bfloat16(v.z), __float2bfloat16(v.w)};
                *(uint2*)&As[row * 64 + c4 * 4] = *(const uint2*)o;
            }
        } else {
            for (int it = 0; it < 4; ++it) {
                int ci = it * 256 + tid, row = ci >> 3, c8 = ci & 7;
                ((uint4*)As)[ci] = *(const uint4*)((const bf16*)val +
                                   (size_t)(v0 + row) * NTOT + k0 + c8 * 8);
            }
        }
        for (int it = 0; it < 4; ++it) {
            int ci = it * 256 + tid, row = ci >> 3, c8 = ci & 7;
            ((uint4*)Bs)[ci] = *(const uint4*)(es + (size_t)(p0 + row) * NTOT + k0 + c8 * 8);
        }
        __syncthreads();
        for (int kk = 0; kk < 2; ++kk) {
            frag a[4], b[4];
            for (int i = 0; i < 4; ++i)
                a[i] = *(const frag*)&As[(wr * 64 + i * 16 + low) * 64 + kk * 32 + quad * 8];
            for (int j = 0; j < 4; ++j)
                b[j] = *(const frag*)&Bs[(wc * 64 + j * 16 + low) * 64 + kk * 32 + quad * 8];
            for (int i = 0; i < 4; ++i)
                for (int j = 0; j < 4; ++j)
                    acc[i][j] = __builtin_amdgcn_mfma_f32_16x16x32_bf16(a[i], b[j], acc[i][j], 0, 0, 0);
        }
        __syncthreads();
    }

    float rs[4];
    for (int j = 0; j < 4; ++j) {
        const int p = p0 + wc * 64 + j * 16 + low;
        rs[j] = (p < PTOT) ? 1.0f / sums[p] : 0.f;
    }
    for (int i = 0; i < 4; ++i)
        for (int r = 0; r < 4; ++r) {
            const int v = v0 + wr * 64 + i * 16 + quad * 4 + r;
            for (int j = 0; j < 4; ++j) {
                const int p = p0 + wc * 64 + j * 16 + low;
                if (p < PTOT)
                    atomicAdd(&out[(size_t)v * PTOT + p], acc[i][j][r] * rs[j]);
            }
        }
}

extern "C" void kernel_launch(void* const* d_in, const int* in_sizes, int n_in,
                              void* d_out, int out_size, void* d_ws, size_t ws_size,
                              hipStream_t stream) {
    const void* mkey = d_in[0];   // memory_key        [64][25920]
    const void* shr  = d_in[1];   // memory_shrinkage  [25920]
    const void* key  = d_in[2];   // key               [64][1620]
    const void* sel  = d_in[3];   // selection         [64][1620]
    const void* val  = d_in[4];   // memory_mask_value [1536][25920]
    float* out = (float*)d_out;

    char* ws = (char*)d_ws;
    unsigned* flag = (unsigned*)(ws + OFF_FLAG);
    bf16*  qf   = (bf16*)(ws + OFF_QF);
    bf16*  nf   = (bf16*)(ws + OFF_NF);
    float* bsq  = (float*)(ws + OFF_BSQ);
    float* msc  = (float*)(ws + OFF_MSC);
    float* sums = (float*)(ws + OFF_SUM);
    bf16*  es   = (bf16*)(ws + OFF_ES);
    bf16*  valb = (bf16*)(ws + OFF_VALB);

    detect_dtype<<<1, 32, 0, stream>>>((const unsigned short*)mkey, flag);
    prep_q<<<(PPAD + 255) / 256, 256, 0, stream>>>(key, sel, qf, bsq, sums, flag);
    prep_n<<<(NPAD + 255) / 256, 256, 0, stream>>>(mkey, shr, nf, msc, flag);
    sim_kernel<<<dim3(NPAD / 128, PPAD / 128), 256, 0, stream>>>(qf, nf, bsq, msc, sums, es);
    if (ws_size >= NEED_BIG) {
        size_t nv = (size_t)VTOT * NTOT;
        conv_val<<<(unsigned)((nv / 8 + 255) / 256), 256, 0, stream>>>(val, valb, flag);
        gemm_big<<<dim3((PPAD2 / 256) * (VTOT / 256) * SPLITS), 512, 0, stream>>>(valb, es, sums, out);
    } else {
        gemm_small<<<dim3(PPAD / 128, VTOT / 128, 8), 256, 0, stream>>>(val, es, sums, out, flag);
    }
}

// Round 6
// 628.205 us; speedup vs baseline: 1.1024x; 1.1024x over previous
//
#include <hip/hip_runtime.h>
#include <hip/hip_bf16.h>

// Cutie memory read: sim = (-mk^2·qe + 2·mk·qk·qe - qe·qk^2)·ms/sqrt(64),
// affinity = softmax_n(sim), out = value @ affinity.
// qe>=0 -> sim <= 0 -> exp(sim) <= 1: no max pass; store es=exp(sim),
// normalize by per-p sum at the end.
// R6: gemm_big 256x256 (512 thr, 8 waves, split-K 6).
// R7: XCD-chunked bijective block swizzle: FETCH 788->134 MB (proven).
// R8/R9: 4-phase counted-vmcnt schedule, exact tail drain (proven, +18%).
// R10: 3-region A (160 KB LDS) + fused normalize (best net, 213 us).
// R11: 2-phase variant: neutral-to-worse (219) -> barriers not the limiter.
// R12: theory = epilogue atomic burst (16.5M device-scope lane-atomics,
//      6 XCD-spread writers/line) is the hidden tail diluting MfmaUtil.
//      Fix: atomic-free split-K -> fp32 partials [SPLITS][V][P] in ws
//      (streamed stores) + reduce6 kernel. Loop restored to R10 4-phase.
//      Fallback to atomic epilogue when ws lacks partial space.

#define NTOT 25920   // memory elements (16*30*54)
#define PTOT 1620    // query pixels (30*54)
#define VTOT 1536    // O*CV = 3*512
#define PPAD 1664    // 13*128 (sim grid padding)
#define PPAD2 1792   // 7*256  (gemm p padding; es has this many rows)
#define NPAD 25984   // 203*128
#define KF   128     // packed feature dim (2*CK)
#define SPLITS 6

typedef __hip_bfloat16 bf16;
using frag  = __attribute__((ext_vector_type(8))) short;   // 8 bf16 = 4 VGPR
using f32x4 = __attribute__((ext_vector_type(4))) float;

#define GLOBAL_AS __attribute__((address_space(1)))
#define LDS_AS    __attribute__((address_space(3)))
__device__ __forceinline__ void async_copy16(void* l, const void* g) {
    // per-lane 16B global chunk -> LDS at (wave-uniform base) + lane*16
    __builtin_amdgcn_global_load_lds((const GLOBAL_AS void*)g, (LDS_AS void*)l,
                                     16, 0, 0);
}

// ---------------- ws layout (bytes) ----------------
#define OFF_FLAG ((size_t)0)                    // u32 dtype flag (64 B reserved)
#define OFF_QF   ((size_t)64)                   // bf16 [PPAD][KF]
#define OFF_NF   ((size_t)426048)               // bf16 [NPAD][KF]
#define OFF_BSQ  ((size_t)7077952)              // f32  [PPAD]
#define OFF_MSC  ((size_t)7084608)              // f32  [NPAD]
#define OFF_SUM  ((size_t)7188544)              // f32  [PPAD]
#define OFF_ACC  ((size_t)7195200)              // f32  [VTOT][PTOT] (unused)
#define OFF_ES   ((size_t)17148480)             // bf16 [PPAD2][NTOT] 92,897,280 B
#define OFF_VALB ((size_t)110045760)            // bf16 [VTOT][NTOT]  79,626,240 B
#define NEED_BIG ((size_t)189672000)
#define OFF_PART ((size_t)189672000)            // f32 [SPLITS][VTOT][PTOT] 59,719,680 B
#define NEED_PART ((size_t)249391680)

// ---- dtype detector (bf16 N(0,1) never has exponent >= 0x8F)
__global__ void detect_dtype(const unsigned short* __restrict__ mk16,
                             unsigned* __restrict__ flag) {
    int i = threadIdx.x;            // 32 threads, parallel loads
    unsigned e = (mk16[2 * i] >> 7) & 0xFFu;
    unsigned long long bad = __ballot(e >= 0x8Fu);
    if (i == 0) *flag = bad ? 1u : 0u;   // 1 = fp32 inputs, 0 = bf16 inputs
}

__device__ __forceinline__ float load_in(const void* p, int idx, bool f32) {
    return f32 ? ((const float*)p)[idx]
               : __bfloat162float(((const bf16*)p)[idx]);
}

// ---- pass 0a: qf[p][c]=-qe, qf[p][64+c]=2*qk*qe; bsq; zero sums
__global__ __launch_bounds__(256) void prep_q(const void* __restrict__ key,
                                              const void* __restrict__ sel,
                                              bf16* __restrict__ qf,
                                              float* __restrict__ bsq,
                                              float* __restrict__ sums,
                                              const unsigned* __restrict__ flag) {
    const bool f32 = (*flag != 0u);
    int p = blockIdx.x * 256 + threadIdx.x;
    if (p >= PPAD) return;
    float acc = 0.f;
    for (int c = 0; c < 64; ++c) {
        float qk = 0.f, qe = 0.f;
        if (p < PTOT) {
            qk = load_in(key, c * PTOT + p, f32);
            qe = load_in(sel, c * PTOT + p, f32);
        }
        qf[p * KF + c]      = __float2bfloat16(-qe);
        qf[p * KF + 64 + c] = __float2bfloat16(2.f * qk * qe);
        acc += qe * qk * qk;
    }
    bsq[p]  = acc;
    sums[p] = 0.f;
}

// ---- pass 0b: nf[n][c]=mk^2, nf[n][64+c]=mk; msc=ms/8
__global__ __launch_bounds__(256) void prep_n(const void* __restrict__ mkey,
                                              const void* __restrict__ shr,
                                              bf16* __restrict__ nf,
                                              float* __restrict__ msc,
                                              const unsigned* __restrict__ flag) {
    const bool f32 = (*flag != 0u);
    int n = blockIdx.x * 256 + threadIdx.x;
    if (n >= NPAD) return;
    for (int c = 0; c < 64; ++c) {
        float mk = (n < NTOT) ? load_in(mkey, c * NTOT + n, f32) : 0.f;
        nf[n * KF + c]      = __float2bfloat16(mk * mk);
        nf[n * KF + 64 + c] = __float2bfloat16(mk);
    }
    msc[n] = (n < NTOT) ? load_in(shr, n, f32) * 0.125f : 0.f;
}

// ---- pass 0c (big path): val -> bf16, 8 elements per thread
__global__ __launch_bounds__(256) void conv_val(const void* __restrict__ val,
                                                bf16* __restrict__ valb,
                                                const unsigned* __restrict__ flag) {
    const bool f32 = (*flag != 0u);
    size_t base = ((size_t)blockIdx.x * 256 + threadIdx.x) * 8;
    if (base >= (size_t)VTOT * NTOT) return;
    if (f32) {
        const float4 v0 = *(const float4*)((const float*)val + base);
        const float4 v1 = *(const float4*)((const float*)val + base + 4);
        bf16 o[8] = {__float2bfloat16(v0.x), __float2bfloat16(v0.y),
                     __float2bfloat16(v0.z), __float2bfloat16(v0.w),
                     __float2bfloat16(v1.x), __float2bfloat16(v1.y),
                     __float2bfloat16(v1.z), __float2bfloat16(v1.w)};
        *(uint4*)(valb + base) = *(const uint4*)o;
    } else {
        *(uint4*)(valb + base) = *(const uint4*)((const bf16*)val + base);
    }
}

// ---- pass 1: sim GEMM (p-tile 128 x n-tile 128, K=128) + exp + row sums
// Swizzled LDS: 16B chunk c of row r stored at chunk position c ^ (r&15).
#define EST_LD 136   // shorts; 272 B row stride, 16B-aligned
__global__ __launch_bounds__(256) void sim_kernel(const bf16* __restrict__ qf,
                                                  const bf16* __restrict__ nf,
                                                  const float* __restrict__ bsq,
                                                  const float* __restrict__ msc,
                                                  float* __restrict__ sums,
                                                  bf16* __restrict__ es) {
    __shared__ __align__(16) char smem[65536];
    short* As  = (short*)smem;            // [128][KF] swizzled
    short* Bs  = (short*)(smem + 32768);  // [128][KF] swizzled
    short* Est = (short*)smem;            // [128][EST_LD] (aliases As/Bs)

    const int tid = threadIdx.x;
    const int nt = blockIdx.x, pt = blockIdx.y;
    const int p0 = pt * 128, n0 = nt * 128;
    const int w = tid >> 6, lane = tid & 63;

    // async stage with source-side swizzle: rows are 256 B = 16 chunks
    for (int it = 0; it < 8; ++it) {
        int rb = it * 16 + w * 4;
        int r  = rb + (lane >> 4);
        int cg = (lane & 15) ^ (r & 15);
        async_copy16(&As[rb * KF], qf + (size_t)(p0 + r) * KF + cg * 8);
    }
    for (int it = 0; it < 8; ++it) {
        int rb = it * 16 + w * 4;
        int r  = rb + (lane >> 4);
        int cg = (lane & 15) ^ (r & 15);
        async_copy16(&Bs[rb * KF], nf + (size_t)(n0 + r) * KF + cg * 8);
    }
    __syncthreads();

    const int low = lane & 15, quad = lane >> 4;
    const int wr = w >> 1, wc = w & 1;

    f32x4 acc[4][4] = {};
    for (int kk = 0; kk < 4; ++kk) {
        frag a[4], b[4];
        for (int i = 0; i < 4; ++i) {
            int row = wr * 64 + i * 16 + low;          // row & 15 == low
            a[i] = *(const frag*)&As[row * KF + (((kk * 4 + quad) ^ low) * 8)];
        }
        for (int j = 0; j < 4; ++j) {
            int row = wc * 64 + j * 16 + low;
            b[j] = *(const frag*)&Bs[row * KF + (((kk * 4 + quad) ^ low) * 8)];
        }
        for (int i = 0; i < 4; ++i)
            for (int j = 0; j < 4; ++j)
                acc[i][j] = __builtin_amdgcn_mfma_f32_16x16x32_bf16(a[i], b[j], acc[i][j], 0, 0, 0);
    }

    float msv[4];
    for (int j = 0; j < 4; ++j) msv[j] = msc[n0 + wc * 64 + j * 16 + low];
    __syncthreads();   // all fragment reads done before Est overwrites As/Bs

    for (int i = 0; i < 4; ++i) {
        const int prow = p0 + wr * 64 + i * 16 + quad * 4;
        const float4 bq = *(const float4*)(bsq + prow);
        const float bs[4] = {bq.x, bq.y, bq.z, bq.w};
        for (int r = 0; r < 4; ++r) {
            const int p = prow + r;
            const int rloc = wr * 64 + i * 16 + quad * 4 + r;
            float vsum = 0.f;
            for (int j = 0; j < 4; ++j) {
                const int n = n0 + wc * 64 + j * 16 + low;
                float e = 0.f;
                if (n < NTOT) e = __expf((acc[i][j][r] - bs[r]) * msv[j]);
                vsum += e;
                Est[rloc * EST_LD + wc * 64 + j * 16 + low] = __bfloat16_as_short(__float2bfloat16(e));
            }
            vsum += __shfl_xor(vsum, 1);
            vsum += __shfl_xor(vsum, 2);
            vsum += __shfl_xor(vsum, 4);
            vsum += __shfl_xor(vsum, 8);
            if (p < PTOT && low == 0) atomicAdd(&sums[p], vsum);
        }
    }
    __syncthreads();

    // vectorized store: thread -> (row, half); 8 x uint4 per thread
    const int row = tid >> 1, half = tid & 1;
    const int p = p0 + row;
    if (p < PTOT) {
        bf16* dst = es + (size_t)p * NTOT + n0 + half * 64;
        const short* src = Est + row * EST_LD + half * 64;
        for (int m = 0; m < 8; ++m) {
            int ng = n0 + half * 64 + m * 8;
            if (ng + 8 <= NTOT)
                *(uint4*)(dst + m * 8) = *(const uint4*)(src + m * 8);
        }
    }
}

// ---- pass 2a (big): 256x256 readout GEMM, R10 4-phase loop + R12 epilogue.
// LDS: As[3][2][128*64] (A regions rotate t%3, 96 KB) +
//      Bs[2][2][128*64] (B regions t&1, 64 KB) = 160 KB.
// Per tile t, 4 phases (q): ph0 reads B frags + A i=0,1 & stages A0(t+2);
// ph1 A i=2,3 & A1(t+2); ph2 A i=4,5 & B0(t+2); ph3 A i=6,7 & B1(t+2) +
// vmcnt(8|0). Each phase: barrier; lgkm0; setprio; 16 MFMA; barrier.
// Epilogue: use_part -> normalized fp32 partial stores (atomic-free
// split-K, R12); else atomicAdd into out (fallback).
__global__ __launch_bounds__(512) void gemm_big(const bf16* __restrict__ val,
                                                const bf16* __restrict__ es,
                                                const float* __restrict__ sums,
                                                float* __restrict__ out,
                                                float* __restrict__ part,
                                                int use_part) {
    __shared__ __align__(16) short As[3][2][128 * 64];   // v rows (96 KB)
    __shared__ __align__(16) short Bs[2][2][128 * 64];   // p rows (64 KB)
    const int tid = threadIdx.x;

    // bijective XCD chunking (m204): consecutive orig ids round-robin XCDs.
    const int nwg = (PPAD2 / 256) * (VTOT / 256) * SPLITS;   // 252
    const int orig = blockIdx.x;
    const int xcd = orig & 7;
    const int q8 = nwg >> 3, r8 = nwg & 7;                   // 31, 4
    const int cbase = (xcd < r8) ? xcd * (q8 + 1) : r8 * (q8 + 1) + (xcd - r8) * q8;
    const int wg = cbase + (orig >> 3);
    const int vt = wg % 6;
    const int t2 = wg / 6;
    const int pt = t2 % 7;
    const int s  = t2 / 7;

    const int p0 = pt * 256, v0 = vt * 256;
    const int ks = s * 68;
    const int ke = (ks + 68 < 405) ? ks + 68 : 405;

    const int w = tid >> 6, lane = tid & 63, low = lane & 15, quad = lane >> 4;
    const int wv = w >> 2, wp = w & 3;     // wv: v half (128), wp: p quarter (64)
    const int rA = lane >> 3;              // 0..7 within 8-row group
    const int cgx = (lane & 7) ^ rA;       // swizzled source chunk (rb%8==0)

    // stage one half-tile (128 rows x 64 k) = 2 global_load_lds per wave
    auto stageA = [&](int t, int reg, int h) {
        if (t >= ke) return;
        const int k0 = t * 64;
#pragma unroll
        for (int it = 0; it < 2; ++it) {
            int rb = it * 64 + w * 8;
            async_copy16(&As[reg][h][rb * 64],
                         val + (size_t)(v0 + h * 128 + rb + rA) * NTOT + k0 + cgx * 8);
        }
    };
    auto stageB = [&](int t, int h) {
        if (t >= ke) return;
        const int k0 = t * 64, bb = t & 1;
#pragma unroll
        for (int it = 0; it < 2; ++it) {
            int rb = it * 64 + w * 8;
            async_copy16(&Bs[bb][h][rb * 64],
                         es + (size_t)(p0 + h * 128 + rb + rA) * NTOT + k0 + cgx * 8);
        }
    };

    const int hB = wp >> 1;                 // this wave's B half
    const int rB0 = (wp & 1) * 64 + low;    // B row-in-half base (+ j*16)
    const int c0 = ((0 * 4 + quad) ^ (low & 7)) * 8;   // kk=0 column (shorts)
    const int c1 = ((1 * 4 + quad) ^ (low & 7)) * 8;   // kk=1 column

    f32x4 acc[8][4] = {};

    // prologue: A(ks), B(ks), A(ks+1), B(ks+1); vmcnt(8) -> A(ks),B(ks)
    // landed, A(ks+1),B(ks+1) in flight.
    int cur = ks % 3;                        // A region of tile ks
    int nx1 = (cur + 1 == 3) ? 0 : cur + 1;  // region of ks+1
    stageA(ks, cur, 0); stageA(ks, cur, 1);
    stageB(ks, 0);      stageB(ks, 1);
    stageA(ks + 1, nx1, 0); stageA(ks + 1, nx1, 1);
    stageB(ks + 1, 0);      stageB(ks + 1, 1);
    asm volatile("s_waitcnt vmcnt(8)" ::: "memory");
    __builtin_amdgcn_s_barrier();

    for (int t = ks; t < ke; ++t) {
        int nx2 = cur + 2; if (nx2 >= 3) nx2 -= 3;   // region of t+2
        const short* Ab = As[cur][wv];
        const short* Bb = Bs[t & 1][hB];
        frag bfr[2][4];                      // B held in regs across all phases

#pragma unroll
        for (int q = 0; q < 4; ++q) {
            // ---- LDS -> reg reads for this phase
            if (q == 0) {
#pragma unroll
                for (int j = 0; j < 4; ++j) {
                    bfr[0][j] = *(const frag*)&Bb[(rB0 + j * 16) * 64 + c0];
                    bfr[1][j] = *(const frag*)&Bb[(rB0 + j * 16) * 64 + c1];
                }
            }
            frag a00, a01, a10, a11;         // i = 2q, 2q+1; kk = 0,1
            {
                const short* r0 = &Ab[((2 * q) * 16 + low) * 64];
                const short* r1 = &Ab[((2 * q + 1) * 16 + low) * 64];
                a00 = *(const frag*)&r0[c0];
                a01 = *(const frag*)&r0[c1];
                a10 = *(const frag*)&r1[c0];
                a11 = *(const frag*)&r1[c1];
            }
            // ---- stage for this phase (regions freed by barrier discipline:
            // A region nx2 held A(t-1), fully read by t-1 q3 + barrier;
            // B region t&1 held B(t), fully read at q0 + barrier.)
            if (q == 0)      stageA(t + 2, nx2, 0);
            else if (q == 1) stageA(t + 2, nx2, 1);
            else if (q == 2) stageB(t + 2, 0);
            else             stageB(t + 2, 1);

            if (q == 0)   // 12 ds_reads this phase: let 4 retire pre-barrier
                asm volatile("s_waitcnt lgkmcnt(8)" ::: "memory");
            __builtin_amdgcn_s_barrier();
            asm volatile("s_waitcnt lgkmcnt(0)" ::: "memory");
            __builtin_amdgcn_s_setprio(1);
#pragma unroll
            for (int j = 0; j < 4; ++j) {
                acc[2 * q][j]     = __builtin_amdgcn_mfma_f32_16x16x32_bf16(a00, bfr[0][j], acc[2 * q][j], 0, 0, 0);
                acc[2 * q][j]     = __builtin_amdgcn_mfma_f32_16x16x32_bf16(a01, bfr[1][j], acc[2 * q][j], 0, 0, 0);
                acc[2 * q + 1][j] = __builtin_amdgcn_mfma_f32_16x16x32_bf16(a10, bfr[0][j], acc[2 * q + 1][j], 0, 0, 0);
                acc[2 * q + 1][j] = __builtin_amdgcn_mfma_f32_16x16x32_bf16(a11, bfr[1][j], acc[2 * q + 1][j], 0, 0, 0);
            }
            __builtin_amdgcn_s_setprio(0);
            if (q == 3) {
                // Exact drain ledger (proven R9): steady leaves A(t+2),B(t+2)
                // (newest 8) in flight; tail drains fully.
                if (t + 2 < ke)
                    asm volatile("s_waitcnt vmcnt(8)" ::: "memory");
                else
                    asm volatile("s_waitcnt vmcnt(0)" ::: "memory");
            }
            __builtin_amdgcn_s_barrier();
        }
        cur = nx1; nx1 = nx2;
    }

    // epilogue: normalized results; partials (atomic-free) or atomics
    float rs[4];
#pragma unroll
    for (int j = 0; j < 4; ++j) {
        const int p = p0 + wp * 64 + j * 16 + low;
        rs[j] = (p < PTOT) ? 1.0f / sums[p] : 0.f;
    }
    if (use_part) {
        float* dst = part + (size_t)s * VTOT * PTOT;
#pragma unroll
        for (int i = 0; i < 8; ++i)
#pragma unroll
            for (int r = 0; r < 4; ++r) {
                const int v = v0 + wv * 128 + i * 16 + quad * 4 + r;
#pragma unroll
                for (int j = 0; j < 4; ++j) {
                    const int p = p0 + wp * 64 + j * 16 + low;
                    if (p < PTOT)
                        dst[(size_t)v * PTOT + p] = acc[i][j][r] * rs[j];
                }
            }
    } else {
#pragma unroll
        for (int i = 0; i < 8; ++i)
#pragma unroll
            for (int r = 0; r < 4; ++r) {
                const int v = v0 + wv * 128 + i * 16 + quad * 4 + r;
#pragma unroll
                for (int j = 0; j < 4; ++j) {
                    const int p = p0 + wp * 64 + j * 16 + low;
                    if (p < PTOT)
                        atomicAdd(&out[(size_t)v * PTOT + p], acc[i][j][r] * rs[j]);
                }
            }
    }
}

// ---- pass 2c (R12): sum the 6 split-K partials -> out (float4 lanes)
__global__ __launch_bounds__(256) void reduce6(const float* __restrict__ part,
                                               float* __restrict__ out) {
    size_t i = ((size_t)blockIdx.x * 256 + threadIdx.x) * 4;
    if (i >= (size_t)VTOT * PTOT) return;
    float4 a = *(const float4*)(part + i);
#pragma unroll
    for (int s = 1; s < SPLITS; ++s) {
        const float4 b = *(const float4*)(part + (size_t)s * VTOT * PTOT + i);
        a.x += b.x; a.y += b.y; a.z += b.z; a.w += b.w;
    }
    *(float4*)(out + i) = a;
}

// ---- pass 2b (small ws): fallback readout GEMM (128-tiles, unswizzled)
__global__ __launch_bounds__(256) void gemm_small(const void* __restrict__ val,
                                                  const bf16* __restrict__ es,
                                                  const float* __restrict__ sums,
                                                  float* __restrict__ out,
                                                  const unsigned* __restrict__ flag) {
    __shared__ short As[128 * 64];
    __shared__ short Bs[128 * 64];
    const bool f32 = (*flag != 0u);
    const int tid = threadIdx.x;
    const int pt = blockIdx.x, vt = blockIdx.y, s = blockIdx.z;
    const int p0 = pt * 128, v0 = vt * 128;
    const int ks = s * 51;
    const int ke = (ks + 51 < 405) ? ks + 51 : 405;

    const int w = tid >> 6, lane = tid & 63, low = lane & 15, quad = lane >> 4;
    const int wr = w >> 1, wc = w & 1;

    f32x4 acc[4][4] = {};
    for (int kt = ks; kt < ke; ++kt) {
        const int k0 = kt * 64;
        if (f32) {
            for (int it = 0; it < 8; ++it) {
                int ci = it * 256 + tid, row = ci >> 4, c4 = ci & 15;
                const float4 v = *(const float4*)((const float*)val +
                                  (size_t)(v0 + row) * NTOT + k0 + c4 * 4);
                bf16 o[4] = {__float2bfloat16(v.x), __float2bfloat16(v.y),
                             __float2bfloat16(v.z), __float2bfloat16(v.w)};
                *(uint2*)&As[row * 64 + c4 * 4] = *(const uint2*)o;
            }
        } else {
            for (int it = 0; it < 4; ++it) {
                int ci = it * 256 + tid, row = ci >> 3, c8 = ci & 7;
                ((uint4*)As)[ci] = *(const uint4*)((const bf16*)val +
                                   (size_t)(v0 + row) * NTOT + k0 + c8 * 8);
            }
        }
        for (int it = 0; it < 4; ++it) {
            int ci = it * 256 + tid, row = ci >> 3, c8 = ci & 7;
            ((uint4*)Bs)[ci] = *(const uint4*)(es + (size_t)(p0 + row) * NTOT + k0 + c8 * 8);
        }
        __syncthreads();
        for (int kk = 0; kk < 2; ++kk) {
            frag a[4], b[4];
            for (int i = 0; i < 4; ++i)
                a[i] = *(const frag*)&As[(wr * 64 + i * 16 + low) * 64 + kk * 32 + quad * 8];
            for (int j = 0; j < 4; ++j)
                b[j] = *(const frag*)&Bs[(wc * 64 + j * 16 + low) * 64 + kk * 32 + quad * 8];
            for (int i = 0; i < 4; ++i)
                for (int j = 0; j < 4; ++j)
                    acc[i][j] = __builtin_amdgcn_mfma_f32_16x16x32_bf16(a[i], b[j], acc[i][j], 0, 0, 0);
        }
        __syncthreads();
    }

    float rs[4];
    for (int j = 0; j < 4; ++j) {
        const int p = p0 + wc * 64 + j * 16 + low;
        rs[j] = (p < PTOT) ? 1.0f / sums[p] : 0.f;
    }
    for (int i = 0; i < 4; ++i)
        for (int r = 0; r < 4; ++r) {
            const int v = v0 + wr * 64 + i * 16 + quad * 4 + r;
            for (int j = 0; j < 4; ++j) {
                const int p = p0 + wc * 64 + j * 16 + low;
                if (p < PTOT)
                    atomicAdd(&out[(size_t)v * PTOT + p], acc[i][j][r] * rs[j]);
            }
        }
}

extern "C" void kernel_launch(void* const* d_in, const int* in_sizes, int n_in,
                              void* d_out, int out_size, void* d_ws, size_t ws_size,
                              hipStream_t stream) {
    const void* mkey = d_in[0];   // memory_key        [64][25920]
    const void* shr  = d_in[1];   // memory_shrinkage  [25920]
    const void* key  = d_in[2];   // key               [64][1620]
    const void* sel  = d_in[3];   // selection         [64][1620]
    const void* val  = d_in[4];   // memory_mask_value [1536][25920]
    float* out = (float*)d_out;

    char* ws = (char*)d_ws;
    unsigned* flag = (unsigned*)(ws + OFF_FLAG);
    bf16*  qf   = (bf16*)(ws + OFF_QF);
    bf16*  nf   = (bf16*)(ws + OFF_NF);
    float* bsq  = (float*)(ws + OFF_BSQ);
    float* msc  = (float*)(ws + OFF_MSC);
    float* sums = (float*)(ws + OFF_SUM);
    bf16*  es   = (bf16*)(ws + OFF_ES);
    bf16*  valb = (bf16*)(ws + OFF_VALB);
    float* part = (float*)(ws + OFF_PART);

    detect_dtype<<<1, 32, 0, stream>>>((const unsigned short*)mkey, flag);
    prep_q<<<(PPAD + 255) / 256, 256, 0, stream>>>(key, sel, qf, bsq, sums, flag);
    prep_n<<<(NPAD + 255) / 256, 256, 0, stream>>>(mkey, shr, nf, msc, flag);
    sim_kernel<<<dim3(NPAD / 128, PPAD / 128), 256, 0, stream>>>(qf, nf, bsq, msc, sums, es);
    if (ws_size >= NEED_BIG) {
        size_t nv = (size_t)VTOT * NTOT;
        conv_val<<<(unsigned)((nv / 8 + 255) / 256), 256, 0, stream>>>(val, valb, flag);
        const int upart = (ws_size >= NEED_PART) ? 1 : 0;
        gemm_big<<<dim3((PPAD2 / 256) * (VTOT / 256) * SPLITS), 512, 0, stream>>>(
            valb, es, sums, out, part, upart);
        if (upart) {
            unsigned nred = (unsigned)(((size_t)VTOT * PTOT / 4 + 255) / 256);
            reduce6<<<nred, 256, 0, stream>>>(part, out);
        }
    } else {
        gemm_small<<<dim3(PPAD / 128, VTOT / 128, 8), 256, 0, stream>>>(val, es, sums, out, flag);
    }
}

// Round 7
// 576.534 us; speedup vs baseline: 1.2012x; 1.0896x over previous
//
#include <hip/hip_runtime.h>
#include <hip/hip_bf16.h>

// Cutie memory read: sim = (-mk^2·qe + 2·mk·qk·qe - qe·qk^2)·ms/sqrt(64),
// affinity = softmax_n(sim), out = value @ affinity.
// qe>=0 -> sim <= 0 -> exp(sim) <= 1: no max pass; store es=exp(sim),
// normalize by per-p sum at the end.
// R7: XCD-chunked bijective block swizzle: FETCH 788->134 MB (proven).
// R8/R9: counted-vmcnt schedule, exact tail drain (proven, +18%).
// R10: 3-region A (160 KB LDS) + fused normalize (proven).
// R12: atomic-free split-K partials + reduce6: gemm 213->149 us (proven).
// R13: sim_kernel restructured (was 152 us @ 2.8% MfmaUtil, latency/atomic
//      bound): 29x13 grid, 7-n-tile chunk loop per block, dbuf nf staging
//      with stage-at-end + uniform vmcnt(8) gate, raw barriers, setprio;
//      sums atomics -> register accumulation + spart[58][PPAD] partials +
//      reduce_sums kernel. qf tile staged once per block.

#define NTOT 25920   // memory elements (16*30*54)
#define PTOT 1620    // query pixels (30*54)
#define VTOT 1536    // O*CV = 3*512
#define PPAD 1664    // 13*128 (sim grid padding)
#define PPAD2 1792   // 7*256  (gemm p padding; es has this many rows)
#define NPAD 25984   // 203*128
#define KF   128     // packed feature dim (2*CK)
#define SPLITS 6
#define NT_CH 7      // n-tiles per sim chunk
#define NCHUNK 29    // 29*7*128 = 25984 = NPAD

typedef __hip_bfloat16 bf16;
using frag  = __attribute__((ext_vector_type(8))) short;   // 8 bf16 = 4 VGPR
using f32x4 = __attribute__((ext_vector_type(4))) float;

#define GLOBAL_AS __attribute__((address_space(1)))
#define LDS_AS    __attribute__((address_space(3)))
__device__ __forceinline__ void async_copy16(void* l, const void* g) {
    // per-lane 16B global chunk -> LDS at (wave-uniform base) + lane*16
    __builtin_amdgcn_global_load_lds((const GLOBAL_AS void*)g, (LDS_AS void*)l,
                                     16, 0, 0);
}

// ---------------- ws layout (bytes) ----------------
#define OFF_FLAG ((size_t)0)                    // u32 dtype flag (64 B reserved)
#define OFF_QF   ((size_t)64)                   // bf16 [PPAD][KF]
#define OFF_NF   ((size_t)426048)               // bf16 [NPAD][KF]
#define OFF_BSQ  ((size_t)7077952)              // f32  [PPAD]
#define OFF_MSC  ((size_t)7084608)              // f32  [NPAD]
#define OFF_SUM  ((size_t)7188544)              // f32  [PPAD]
#define OFF_ACC  ((size_t)7195200)              // f32  spart [2*NCHUNK][PPAD]
#define OFF_ES   ((size_t)17148480)             // bf16 [PPAD2][NTOT] 92,897,280 B
#define OFF_VALB ((size_t)110045760)            // bf16 [VTOT][NTOT]  79,626,240 B
#define NEED_BIG ((size_t)189672000)
#define OFF_PART ((size_t)189672000)            // f32 [SPLITS][VTOT][PTOT] 59,719,680 B
#define NEED_PART ((size_t)249391680)

// ---- dtype detector (bf16 N(0,1) never has exponent >= 0x8F)
__global__ void detect_dtype(const unsigned short* __restrict__ mk16,
                             unsigned* __restrict__ flag) {
    int i = threadIdx.x;            // 32 threads, parallel loads
    unsigned e = (mk16[2 * i] >> 7) & 0xFFu;
    unsigned long long bad = __ballot(e >= 0x8Fu);
    if (i == 0) *flag = bad ? 1u : 0u;   // 1 = fp32 inputs, 0 = bf16 inputs
}

__device__ __forceinline__ float load_in(const void* p, int idx, bool f32) {
    return f32 ? ((const float*)p)[idx]
               : __bfloat162float(((const bf16*)p)[idx]);
}

// ---- pass 0a: qf[p][c]=-qe, qf[p][64+c]=2*qk*qe; bsq; zero sums
__global__ __launch_bounds__(256) void prep_q(const void* __restrict__ key,
                                              const void* __restrict__ sel,
                                              bf16* __restrict__ qf,
                                              float* __restrict__ bsq,
                                              float* __restrict__ sums,
                                              const unsigned* __restrict__ flag) {
    const bool f32 = (*flag != 0u);
    int p = blockIdx.x * 256 + threadIdx.x;
    if (p >= PPAD) return;
    float acc = 0.f;
    for (int c = 0; c < 64; ++c) {
        float qk = 0.f, qe = 0.f;
        if (p < PTOT) {
            qk = load_in(key, c * PTOT + p, f32);
            qe = load_in(sel, c * PTOT + p, f32);
        }
        qf[p * KF + c]      = __float2bfloat16(-qe);
        qf[p * KF + 64 + c] = __float2bfloat16(2.f * qk * qe);
        acc += qe * qk * qk;
    }
    bsq[p]  = acc;
    sums[p] = 0.f;
}

// ---- pass 0b: nf[n][c]=mk^2, nf[n][64+c]=mk; msc=ms/8
__global__ __launch_bounds__(256) void prep_n(const void* __restrict__ mkey,
                                              const void* __restrict__ shr,
                                              bf16* __restrict__ nf,
                                              float* __restrict__ msc,
                                              const unsigned* __restrict__ flag) {
    const bool f32 = (*flag != 0u);
    int n = blockIdx.x * 256 + threadIdx.x;
    if (n >= NPAD) return;
    for (int c = 0; c < 64; ++c) {
        float mk = (n < NTOT) ? load_in(mkey, c * NTOT + n, f32) : 0.f;
        nf[n * KF + c]      = __float2bfloat16(mk * mk);
        nf[n * KF + 64 + c] = __float2bfloat16(mk);
    }
    msc[n] = (n < NTOT) ? load_in(shr, n, f32) * 0.125f : 0.f;
}

// ---- pass 0c (big path): val -> bf16, 8 elements per thread
__global__ __launch_bounds__(256) void conv_val(const void* __restrict__ val,
                                                bf16* __restrict__ valb,
                                                const unsigned* __restrict__ flag) {
    const bool f32 = (*flag != 0u);
    size_t base = ((size_t)blockIdx.x * 256 + threadIdx.x) * 8;
    if (base >= (size_t)VTOT * NTOT) return;
    if (f32) {
        const float4 v0 = *(const float4*)((const float*)val + base);
        const float4 v1 = *(const float4*)((const float*)val + base + 4);
        bf16 o[8] = {__float2bfloat16(v0.x), __float2bfloat16(v0.y),
                     __float2bfloat16(v0.z), __float2bfloat16(v0.w),
                     __float2bfloat16(v1.x), __float2bfloat16(v1.y),
                     __float2bfloat16(v1.z), __float2bfloat16(v1.w)};
        *(uint4*)(valb + base) = *(const uint4*)o;
    } else {
        *(uint4*)(valb + base) = *(const uint4*)((const bf16*)val + base);
    }
}

// ---- pass 1 (R13): sim GEMM, chunked. Block (ch, pt): p-tile 128, loops
// 7 n-tiles. LDS: Qs 32K (staged once) + Ns dbuf 64K + Est 34.8K = 131K.
// Per tile: vmcnt(8) gate; barrier; frag reads + 64 MFMA; lgkm0+barrier
// (Ns free); exp + vsum reg-accumulate + Est writes; lgkm0+barrier; es
// store; sched_barrier; stage Ns(t+2) LAST (newest 8 in vmem queue ->
// vmcnt(8) gate is exact for every t incl. tail). Chunk end: shfl-reduce
// vsum, plain store to spart (atomic-free).
#define EST_LD 136   // shorts; 272 B row stride, 16B-aligned
__global__ __launch_bounds__(256) void sim_kernel(const bf16* __restrict__ qf,
                                                  const bf16* __restrict__ nf,
                                                  const float* __restrict__ bsq,
                                                  const float* __restrict__ msc,
                                                  float* __restrict__ spart,
                                                  bf16* __restrict__ es) {
    __shared__ __align__(16) short Qs[128 * KF];        // 32 KB
    __shared__ __align__(16) short Ns[2][128 * KF];     // 64 KB
    __shared__ __align__(16) short Est[128 * EST_LD];   // 34.8 KB

    const int tid = threadIdx.x;
    const int ch = blockIdx.x, pt = blockIdx.y;
    const int p0 = pt * 128;
    const int nbase = ch * (NT_CH * 128);
    const int w = tid >> 6, lane = tid & 63;
    const int low = lane & 15, quad = lane >> 4;
    const int wr = w >> 1, wc = w & 1;

    // stage Qs once (source-side swizzle: chunk cg of row r at cg^(r&15))
    for (int it = 0; it < 8; ++it) {
        int rb = it * 16 + w * 4;
        int r  = rb + (lane >> 4);
        int cg = (lane & 15) ^ (r & 15);
        async_copy16(&Qs[rb * KF], qf + (size_t)(p0 + r) * KF + cg * 8);
    }
    auto stageN = [&](int t) {
        const int n0s = nbase + t * 128;
        short* dst = Ns[t & 1];
        for (int it = 0; it < 8; ++it) {
            int rb = it * 16 + w * 4;
            int r  = rb + (lane >> 4);
            int cg = (lane & 15) ^ (r & 15);
            async_copy16(&dst[rb * KF], nf + (size_t)(n0s + r) * KF + cg * 8);
        }
    };
    stageN(0);
    stageN(1);

    float vs[4][4] = {};    // chunk-accumulated exp row-sums [i][r], per-lane

    for (int t = 0; t < NT_CH; ++t) {
        const int n0 = nbase + t * 128;
        const short* Nb = Ns[t & 1];

        // gate: Ns(t) is never among the newest 8 vmem ops -> drained here
        asm volatile("s_waitcnt vmcnt(8)" ::: "memory");
        __builtin_amdgcn_s_barrier();

        f32x4 acc[4][4] = {};
        __builtin_amdgcn_s_setprio(1);
        for (int kk = 0; kk < 4; ++kk) {
            frag a[4], b[4];
#pragma unroll
            for (int i = 0; i < 4; ++i) {
                int row = wr * 64 + i * 16 + low;          // row & 15 == low
                a[i] = *(const frag*)&Qs[row * KF + (((kk * 4 + quad) ^ low) * 8)];
            }
#pragma unroll
            for (int j = 0; j < 4; ++j) {
                int row = wc * 64 + j * 16 + low;
                b[j] = *(const frag*)&Nb[row * KF + (((kk * 4 + quad) ^ low) * 8)];
            }
#pragma unroll
            for (int i = 0; i < 4; ++i)
#pragma unroll
                for (int j = 0; j < 4; ++j)
                    acc[i][j] = __builtin_amdgcn_mfma_f32_16x16x32_bf16(a[i], b[j], acc[i][j], 0, 0, 0);
        }
        __builtin_amdgcn_s_setprio(0);
        asm volatile("s_waitcnt lgkmcnt(0)" ::: "memory");
        __builtin_amdgcn_s_barrier();      // Ns(t) reads done block-wide

        // exp + accumulate + Est writes (Est readers of t-1 all done: their
        // reads completed before they issued stores last iter + barrier)
        float msv[4];
#pragma unroll
        for (int j = 0; j < 4; ++j) msv[j] = msc[n0 + wc * 64 + j * 16 + low];
#pragma unroll
        for (int i = 0; i < 4; ++i) {
            const int prow = p0 + wr * 64 + i * 16 + quad * 4;
            const float4 bq = *(const float4*)(bsq + prow);
            const float bsv[4] = {bq.x, bq.y, bq.z, bq.w};
#pragma unroll
            for (int r = 0; r < 4; ++r) {
                const int rloc = wr * 64 + i * 16 + quad * 4 + r;
                float vsum = 0.f;
#pragma unroll
                for (int j = 0; j < 4; ++j) {
                    const int n = n0 + wc * 64 + j * 16 + low;
                    float e = 0.f;
                    if (n < NTOT) e = __expf((acc[i][j][r] - bsv[r]) * msv[j]);
                    vsum += e;
                    Est[rloc * EST_LD + wc * 64 + j * 16 + low] =
                        __bfloat16_as_short(__float2bfloat16(e));
                }
                vs[i][r] += vsum;
            }
        }
        asm volatile("s_waitcnt lgkmcnt(0)" ::: "memory");
        __builtin_amdgcn_s_barrier();      // Est complete & visible

        // es store: thread -> (row, half); 8 x uint4. No p-guard: pad rows
        // (p in [PTOT,PPAD)) are allocated in es and discarded by gemm's
        // epilogue guard; uniform instruction count keeps per-wave vmcnt
        // ledgers identical (required for the counted gate).
        {
            const int row = tid >> 1, half = tid & 1;
            bf16* dst = es + (size_t)(p0 + row) * NTOT + n0 + half * 64;
            const short* src = Est + row * EST_LD + half * 64;
#pragma unroll
            for (int m = 0; m < 8; ++m) {
                int ng = n0 + half * 64 + m * 8;
                if (ng + 8 <= NTOT)     // lane-divergent (half) -> still issues
                    *(uint4*)(dst + m * 8) = *(const uint4*)(src + m * 8);
            }
        }
        __builtin_amdgcn_sched_barrier(0);
        if (t + 2 < NT_CH) stageN(t + 2);  // LAST vmem group of the iteration
        __builtin_amdgcn_sched_barrier(0);
    }

    // chunk end: shfl-reduce over low lanes, plain store (atomic-free)
#pragma unroll
    for (int i = 0; i < 4; ++i)
#pragma unroll
        for (int r = 0; r < 4; ++r) {
            float v = vs[i][r];
            v += __shfl_xor(v, 1);
            v += __shfl_xor(v, 2);
            v += __shfl_xor(v, 4);
            v += __shfl_xor(v, 8);
            if (low == 0) {
                const int p = p0 + wr * 64 + i * 16 + quad * 4 + r;
                spart[(size_t)(ch * 2 + wc) * PPAD + p] = v;
            }
        }
}

// ---- pass 1b (R13): sums[p] = sum over 58 chunk-partials (coalesced)
__global__ __launch_bounds__(256) void reduce_sums(const float* __restrict__ spart,
                                                   float* __restrict__ sums) {
    int p = blockIdx.x * 256 + threadIdx.x;
    if (p >= PPAD) return;
    float a = 0.f;
#pragma unroll 4
    for (int k = 0; k < 2 * NCHUNK; ++k) a += spart[(size_t)k * PPAD + p];
    sums[p] = a;
}

// ---- pass 2a (big): 256x256 readout GEMM, R10 4-phase loop + R12 epilogue.
__global__ __launch_bounds__(512) void gemm_big(const bf16* __restrict__ val,
                                                const bf16* __restrict__ es,
                                                const float* __restrict__ sums,
                                                float* __restrict__ out,
                                                float* __restrict__ part,
                                                int use_part) {
    __shared__ __align__(16) short As[3][2][128 * 64];   // v rows (96 KB)
    __shared__ __align__(16) short Bs[2][2][128 * 64];   // p rows (64 KB)
    const int tid = threadIdx.x;

    // bijective XCD chunking (m204): consecutive orig ids round-robin XCDs.
    const int nwg = (PPAD2 / 256) * (VTOT / 256) * SPLITS;   // 252
    const int orig = blockIdx.x;
    const int xcd = orig & 7;
    const int q8 = nwg >> 3, r8 = nwg & 7;                   // 31, 4
    const int cbase = (xcd < r8) ? xcd * (q8 + 1) : r8 * (q8 + 1) + (xcd - r8) * q8;
    const int wg = cbase + (orig >> 3);
    const int vt = wg % 6;
    const int t2 = wg / 6;
    const int pt = t2 % 7;
    const int s  = t2 / 7;

    const int p0 = pt * 256, v0 = vt * 256;
    const int ks = s * 68;
    const int ke = (ks + 68 < 405) ? ks + 68 : 405;

    const int w = tid >> 6, lane = tid & 63, low = lane & 15, quad = lane >> 4;
    const int wv = w >> 2, wp = w & 3;     // wv: v half (128), wp: p quarter (64)
    const int rA = lane >> 3;              // 0..7 within 8-row group
    const int cgx = (lane & 7) ^ rA;       // swizzled source chunk (rb%8==0)

    auto stageA = [&](int t, int reg, int h) {
        if (t >= ke) return;
        const int k0 = t * 64;
#pragma unroll
        for (int it = 0; it < 2; ++it) {
            int rb = it * 64 + w * 8;
            async_copy16(&As[reg][h][rb * 64],
                         val + (size_t)(v0 + h * 128 + rb + rA) * NTOT + k0 + cgx * 8);
        }
    };
    auto stageB = [&](int t, int h) {
        if (t >= ke) return;
        const int k0 = t * 64, bb = t & 1;
#pragma unroll
        for (int it = 0; it < 2; ++it) {
            int rb = it * 64 + w * 8;
            async_copy16(&Bs[bb][h][rb * 64],
                         es + (size_t)(p0 + h * 128 + rb + rA) * NTOT + k0 + cgx * 8);
        }
    };

    const int hB = wp >> 1;                 // this wave's B half
    const int rB0 = (wp & 1) * 64 + low;    // B row-in-half base (+ j*16)
    const int c0 = ((0 * 4 + quad) ^ (low & 7)) * 8;   // kk=0 column (shorts)
    const int c1 = ((1 * 4 + quad) ^ (low & 7)) * 8;   // kk=1 column

    f32x4 acc[8][4] = {};

    int cur = ks % 3;                        // A region of tile ks
    int nx1 = (cur + 1 == 3) ? 0 : cur + 1;  // region of ks+1
    stageA(ks, cur, 0); stageA(ks, cur, 1);
    stageB(ks, 0);      stageB(ks, 1);
    stageA(ks + 1, nx1, 0); stageA(ks + 1, nx1, 1);
    stageB(ks + 1, 0);      stageB(ks + 1, 1);
    asm volatile("s_waitcnt vmcnt(8)" ::: "memory");
    __builtin_amdgcn_s_barrier();

    for (int t = ks; t < ke; ++t) {
        int nx2 = cur + 2; if (nx2 >= 3) nx2 -= 3;   // region of t+2
        const short* Ab = As[cur][wv];
        const short* Bb = Bs[t & 1][hB];
        frag bfr[2][4];                      // B held in regs across all phases

#pragma unroll
        for (int q = 0; q < 4; ++q) {
            if (q == 0) {
#pragma unroll
                for (int j = 0; j < 4; ++j) {
                    bfr[0][j] = *(const frag*)&Bb[(rB0 + j * 16) * 64 + c0];
                    bfr[1][j] = *(const frag*)&Bb[(rB0 + j * 16) * 64 + c1];
                }
            }
            frag a00, a01, a10, a11;         // i = 2q, 2q+1; kk = 0,1
            {
                const short* r0 = &Ab[((2 * q) * 16 + low) * 64];
                const short* r1 = &Ab[((2 * q + 1) * 16 + low) * 64];
                a00 = *(const frag*)&r0[c0];
                a01 = *(const frag*)&r0[c1];
                a10 = *(const frag*)&r1[c0];
                a11 = *(const frag*)&r1[c1];
            }
            if (q == 0)      stageA(t + 2, nx2, 0);
            else if (q == 1) stageA(t + 2, nx2, 1);
            else if (q == 2) stageB(t + 2, 0);
            else             stageB(t + 2, 1);

            if (q == 0)
                asm volatile("s_waitcnt lgkmcnt(8)" ::: "memory");
            __builtin_amdgcn_s_barrier();
            asm volatile("s_waitcnt lgkmcnt(0)" ::: "memory");
            __builtin_amdgcn_s_setprio(1);
#pragma unroll
            for (int j = 0; j < 4; ++j) {
                acc[2 * q][j]     = __builtin_amdgcn_mfma_f32_16x16x32_bf16(a00, bfr[0][j], acc[2 * q][j], 0, 0, 0);
                acc[2 * q][j]     = __builtin_amdgcn_mfma_f32_16x16x32_bf16(a01, bfr[1][j], acc[2 * q][j], 0, 0, 0);
                acc[2 * q + 1][j] = __builtin_amdgcn_mfma_f32_16x16x32_bf16(a10, bfr[0][j], acc[2 * q + 1][j], 0, 0, 0);
                acc[2 * q + 1][j] = __builtin_amdgcn_mfma_f32_16x16x32_bf16(a11, bfr[1][j], acc[2 * q + 1][j], 0, 0, 0);
            }
            __builtin_amdgcn_s_setprio(0);
            if (q == 3) {
                if (t + 2 < ke)
                    asm volatile("s_waitcnt vmcnt(8)" ::: "memory");
                else
                    asm volatile("s_waitcnt vmcnt(0)" ::: "memory");
            }
            __builtin_amdgcn_s_barrier();
        }
        cur = nx1; nx1 = nx2;
    }

    float rs[4];
#pragma unroll
    for (int j = 0; j < 4; ++j) {
        const int p = p0 + wp * 64 + j * 16 + low;
        rs[j] = (p < PTOT) ? 1.0f / sums[p] : 0.f;
    }
    if (use_part) {
        float* dst = part + (size_t)s * VTOT * PTOT;
#pragma unroll
        for (int i = 0; i < 8; ++i)
#pragma unroll
            for (int r = 0; r < 4; ++r) {
                const int v = v0 + wv * 128 + i * 16 + quad * 4 + r;
#pragma unroll
                for (int j = 0; j < 4; ++j) {
                    const int p = p0 + wp * 64 + j * 16 + low;
                    if (p < PTOT)
                        dst[(size_t)v * PTOT + p] = acc[i][j][r] * rs[j];
                }
            }
    } else {
#pragma unroll
        for (int i = 0; i < 8; ++i)
#pragma unroll
            for (int r = 0; r < 4; ++r) {
                const int v = v0 + wv * 128 + i * 16 + quad * 4 + r;
#pragma unroll
                for (int j = 0; j < 4; ++j) {
                    const int p = p0 + wp * 64 + j * 16 + low;
                    if (p < PTOT)
                        atomicAdd(&out[(size_t)v * PTOT + p], acc[i][j][r] * rs[j]);
                }
            }
    }
}

// ---- pass 2c (R12): sum the 6 split-K partials -> out (float4 lanes)
__global__ __launch_bounds__(256) void reduce6(const float* __restrict__ part,
                                               float* __restrict__ out) {
    size_t i = ((size_t)blockIdx.x * 256 + threadIdx.x) * 4;
    if (i >= (size_t)VTOT * PTOT) return;
    float4 a = *(const float4*)(part + i);
#pragma unroll
    for (int s = 1; s < SPLITS; ++s) {
        const float4 b = *(const float4*)(part + (size_t)s * VTOT * PTOT + i);
        a.x += b.x; a.y += b.y; a.z += b.z; a.w += b.w;
    }
    *(float4*)(out + i) = a;
}

// ---- pass 2b (small ws): fallback readout GEMM (128-tiles, unswizzled)
__global__ __launch_bounds__(256) void gemm_small(const void* __restrict__ val,
                                                  const bf16* __restrict__ es,
                                                  const float* __restrict__ sums,
                                                  float* __restrict__ out,
                                                  const unsigned* __restrict__ flag) {
    __shared__ short As[128 * 64];
    __shared__ short Bs[128 * 64];
    const bool f32 = (*flag != 0u);
    const int tid = threadIdx.x;
    const int pt = blockIdx.x, vt = blockIdx.y, s = blockIdx.z;
    const int p0 = pt * 128, v0 = vt * 128;
    const int ks = s * 51;
    const int ke = (ks + 51 < 405) ? ks + 51 : 405;

    const int w = tid >> 6, lane = tid & 63, low = lane & 15, quad = lane >> 4;
    const int wr = w >> 1, wc = w & 1;

    f32x4 acc[4][4] = {};
    for (int kt = ks; kt < ke; ++kt) {
        const int k0 = kt * 64;
        if (f32) {
            for (int it = 0; it < 8; ++it) {
                int ci = it * 256 + tid, row = ci >> 4, c4 = ci & 15;
                const float4 v = *(const float4*)((const float*)val +
                                  (size_t)(v0 + row) * NTOT + k0 + c4 * 4);
                bf16 o[4] = {__float2bfloat16(v.x), __float2bfloat16(v.y),
                             __float2bfloat16(v.z), __float2bfloat16(v.w)};
                *(uint2*)&As[row * 64 + c4 * 4] = *(const uint2*)o;
            }
        } else {
            for (int it = 0; it < 4; ++it) {
                int ci = it * 256 + tid, row = ci >> 3, c8 = ci & 7;
                ((uint4*)As)[ci] = *(const uint4*)((const bf16*)val +
                                   (size_t)(v0 + row) * NTOT + k0 + c8 * 8);
            }
        }
        for (int it = 0; it < 4; ++it) {
            int ci = it * 256 + tid, row = ci >> 3, c8 = ci & 7;
            ((uint4*)Bs)[ci] = *(const uint4*)(es + (size_t)(p0 + row) * NTOT + k0 + c8 * 8);
        }
        __syncthreads();
        for (int kk = 0; kk < 2; ++kk) {
            frag a[4], b[4];
            for (int i = 0; i < 4; ++i)
                a[i] = *(const frag*)&As[(wr * 64 + i * 16 + low) * 64 + kk * 32 + quad * 8];
            for (int j = 0; j < 4; ++j)
                b[j] = *(const frag*)&Bs[(wc * 64 + j * 16 + low) * 64 + kk * 32 + quad * 8];
            for (int i = 0; i < 4; ++i)
                for (int j = 0; j < 4; ++j)
                    acc[i][j] = __builtin_amdgcn_mfma_f32_16x16x32_bf16(a[i], b[j], acc[i][j], 0, 0, 0);
        }
        __syncthreads();
    }

    float rs[4];
    for (int j = 0; j < 4; ++j) {
        const int p = p0 + wc * 64 + j * 16 + low;
        rs[j] = (p < PTOT) ? 1.0f / sums[p] : 0.f;
    }
    for (int i = 0; i < 4; ++i)
        for (int r = 0; r < 4; ++r) {
            const int v = v0 + wr * 64 + i * 16 + quad * 4 + r;
            for (int j = 0; j < 4; ++j) {
                const int p = p0 + wc * 64 + j * 16 + low;
                if (p < PTOT)
                    atomicAdd(&out[(size_t)v * PTOT + p], acc[i][j][r] * rs[j]);
            }
        }
}

extern "C" void kernel_launch(void* const* d_in, const int* in_sizes, int n_in,
                              void* d_out, int out_size, void* d_ws, size_t ws_size,
                              hipStream_t stream) {
    const void* mkey = d_in[0];   // memory_key        [64][25920]
    const void* shr  = d_in[1];   // memory_shrinkage  [25920]
    const void* key  = d_in[2];   // key               [64][1620]
    const void* sel  = d_in[3];   // selection         [64][1620]
    const void* val  = d_in[4];   // memory_mask_value [1536][25920]
    float* out = (float*)d_out;

    char* ws = (char*)d_ws;
    unsigned* flag = (unsigned*)(ws + OFF_FLAG);
    bf16*  qf   = (bf16*)(ws + OFF_QF);
    bf16*  nf   = (bf16*)(ws + OFF_NF);
    float* bsq  = (float*)(ws + OFF_BSQ);
    float* msc  = (float*)(ws + OFF_MSC);
    float* sums = (float*)(ws + OFF_SUM);
    float* spart = (float*)(ws + OFF_ACC);
    bf16*  es   = (bf16*)(ws + OFF_ES);
    bf16*  valb = (bf16*)(ws + OFF_VALB);
    float* part = (float*)(ws + OFF_PART);

    detect_dtype<<<1, 32, 0, stream>>>((const unsigned short*)mkey, flag);
    prep_q<<<(PPAD + 255) / 256, 256, 0, stream>>>(key, sel, qf, bsq, sums, flag);
    prep_n<<<(NPAD + 255) / 256, 256, 0, stream>>>(mkey, shr, nf, msc, flag);
    sim_kernel<<<dim3(NCHUNK, PPAD / 128), 256, 0, stream>>>(qf, nf, bsq, msc, spart, es);
    reduce_sums<<<(PPAD + 255) / 256, 256, 0, stream>>>(spart, sums);
    if (ws_size >= NEED_BIG) {
        size_t nv = (size_t)VTOT * NTOT;
        conv_val<<<(unsigned)((nv / 8 + 255) / 256), 256, 0, stream>>>(val, valb, flag);
        const int upart = (ws_size >= NEED_PART) ? 1 : 0;
        gemm_big<<<dim3((PPAD2 / 256) * (VTOT / 256) * SPLITS), 512, 0, stream>>>(
            valb, es, sums, out, part, upart);
        if (upart) {
            unsigned nred = (unsigned)(((size_t)VTOT * PTOT / 4 + 255) / 256);
            reduce6<<<nred, 256, 0, stream>>>(part, out);
        }
    } else {
        gemm_small<<<dim3(PPAD / 128, VTOT / 128, 8), 256, 0, stream>>>(val, es, sums, out, flag);
    }
}